// Round 9
// baseline (3293.287 us; speedup 1.0000x reference)
//
#include <hip/hip_runtime.h>
#include <hip/hip_cooperative_groups.h>
#include <math.h>

#define HIDDEN 16
#define CIN 5
#define BB 8
#define TT 12
#define HH 256
#define WW 256
#define TX 32
#define TY 8
#define HALO_X 34
#define HALO_Y 10
#define NPX (HALO_X * HALO_Y)   // 340 staged pixels
#define STRIDE 40               // shorts per px row: 80 B -> max 2-way bank aliasing (free)
#define NTILE 2048
#define NBLKP 768               // persistent blocks = 3 per CU (co-resident)

typedef __attribute__((ext_vector_type(8))) short bf16x8;
typedef __attribute__((ext_vector_type(4))) float floatx4;

__device__ __forceinline__ unsigned short f2bf(float f) {   // RNE fp32->bf16
    unsigned int u = __float_as_uint(f);
    u += 0x7fffu + ((u >> 16) & 1u);
    return (unsigned short)(u >> 16);
}
__device__ __forceinline__ float bf2f(unsigned short s) {
    return __uint_as_float(((unsigned int)s) << 16);
}
__device__ __forceinline__ float fast_sigmoid(float x) { return 1.0f / (1.0f + __expf(-x)); }
__device__ __forceinline__ float fast_tanh(float x) {
    float e2 = __expf(-2.0f * fabsf(x));
    float t = (1.0f - e2) / (1.0f + e2);
    return copysignf(t, x);
}

// Pack W_cell [64][21][3][3] into B-fragment layout for mfma_f32_16x16x32_bf16:
// Wfrag[tap][gate][lane][j]; lane holds B[k=(lane>>4)*8+j][col=lane&15].
// k-order: 0..15 = h units (ci_ref 5+k), 16..20 = x chans, 21..31 = 0.
__global__ void prep_w_kernel(const float* __restrict__ Wc,
                              unsigned short* __restrict__ Wfrag) {
    int i = blockIdx.x * 256 + threadIdx.x;
    if (i >= 9 * 4 * 64 * 8) return;
    int j    = i & 7;
    int lane = (i >> 3) & 63;
    int g    = (i >> 9) & 3;
    int tap  = i >> 11;
    int k    = ((lane >> 4) << 3) + j;
    int col  = lane & 15;
    int o    = g * 16 + col;
    float w  = 0.0f;
    if (k < 21) {
        int ci_ref = (k < 16) ? (5 + k) : (k - 16);
        w = Wc[(o * 21 + ci_ref) * 9 + tap];
    }
    Wfrag[i] = f2bf(w);
}

// One-time x repack: planar fp32 [b][t][c][y][x] -> channel-last bf16 [b][t][y][x][8]
__global__ void prep_x_kernel(const float* __restrict__ x,
                              unsigned short* __restrict__ xp) {
    size_t n = (size_t)blockIdx.x * 256 + threadIdx.x;
    const size_t TOTPX = (size_t)BB * TT * HH * WW;
    if (n >= TOTPX) return;
    size_t bt  = n / (size_t)(HH * WW);
    size_t pix = n - bt * (size_t)(HH * WW);
    const float* src = x + bt * (size_t)CIN * HH * WW + pix;
    unsigned short v[8];
    #pragma unroll
    for (int c = 0; c < CIN; ++c) v[c] = f2bf(src[(size_t)c * HH * WW]);
    v[5] = 0; v[6] = 0; v[7] = 0;
    *(uint4*)&xp[n * 8] = *(const uint4*)v;
}

__global__ void init_flags_kernel(unsigned int* __restrict__ flags) {
    int i = blockIdx.x * 256 + threadIdx.x;
    if (i < TT * NTILE) flags[i] = 0u;
}

// Stage one 32x8 tile (+halo) into LDS: [px][k] bf16, k = 16 h + 5 x + pad.
__device__ __forceinline__ void stage_tile(unsigned short* __restrict__ dst,
                                           int tid, int bb, int y0, int x0,
                                           int t, int first,
                                           const unsigned short* __restrict__ xp,
                                           const unsigned short* __restrict__ h_rd) {
    for (int i = tid; i < NPX; i += 256) {
        int ly = i / HALO_X;
        int lx = i - ly * HALO_X;
        int gy = y0 + ly - 1;
        int gx = x0 + lx - 1;
        bool inb = (gy >= 0 && gy < HH && gx >= 0 && gx < WW);
        unsigned short* row = &dst[i * STRIDE];
        uint4 z = {0, 0, 0, 0};
        if (inb && !first) {
            size_t hb = ((size_t)bb * HH * WW + (size_t)gy * WW + gx) * HIDDEN;
            *(uint4*)&row[0] = *(const uint4*)&h_rd[hb];
            *(uint4*)&row[8] = *(const uint4*)&h_rd[hb + 8];
        } else {
            *(uint4*)&row[0] = z;
            *(uint4*)&row[8] = z;
        }
        if (inb) {
            size_t xb = (((size_t)bb * TT + t) * (size_t)(HH * WW)
                         + (size_t)gy * WW + gx) * 8;
            *(uint4*)&row[16] = *(const uint4*)&xp[xb];
        } else {
            *(uint4*)&row[16] = z;
        }
        *(uint4*)&row[24] = z;
    }
}

// Half-split implicit-GEMM conv + fused gates; cv[4] carries c (floatx4 per strip).
__device__ __forceinline__ void compute_tile(const unsigned short* __restrict__ buf,
                                             const unsigned short* __restrict__ Wfrag,
                                             const float* __restrict__ bg,
                                             const int* __restrict__ abase,
                                             int bb, int y0, int x0,
                                             int lane, int wave, int u, int quad,
                                             floatx4* __restrict__ cv,
                                             unsigned short* __restrict__ h_wr) {
    #pragma unroll 1
    for (int half = 0; half < 2; ++half) {
        floatx4 acc[2][4];
        #pragma unroll
        for (int mh = 0; mh < 2; ++mh)
            #pragma unroll
            for (int g = 0; g < 4; ++g)
                acc[mh][g] = (floatx4){bg[g], bg[g], bg[g], bg[g]};

        #pragma unroll 3
        for (int tap = 0; tap < 9; ++tap) {
            int ky = tap / 3;
            int kx = tap - ky * 3;
            int toff = (ky * HALO_X + kx) * STRIDE;
            bf16x8 bfr[4];
            #pragma unroll
            for (int g = 0; g < 4; ++g)
                bfr[g] = *(const bf16x8*)&Wfrag[(size_t)((tap * 4 + g) * 64 + lane) * 8];
            #pragma unroll
            for (int mh = 0; mh < 2; ++mh) {
                bf16x8 af = *(const bf16x8*)&buf[abase[half * 2 + mh] + toff];
                #pragma unroll
                for (int g = 0; g < 4; ++g)
                    acc[mh][g] = __builtin_amdgcn_mfma_f32_16x16x32_bf16(
                        af, bfr[g], acc[mh][g], 0, 0, 0);
            }
        }

        #pragma unroll
        for (int mh = 0; mh < 2; ++mh) {
            int ml = half * 2 + mh;
            int m  = wave + ml * 4;
            int my = m >> 1;
            int mx = (m & 1) << 4;
            int py = y0 + my;
            #pragma unroll
            for (int r = 0; r < 4; ++r) {
                int pxx = x0 + mx + quad * 4 + r;
                size_t idx = ((size_t)bb * HH * WW + (size_t)py * WW + pxx) * HIDDEN + u;
                float ig = fast_sigmoid(acc[mh][0][r]);
                float fg = fast_sigmoid(acc[mh][1][r]);
                float og = fast_sigmoid(acc[mh][2][r]);
                float gg = fast_tanh(acc[mh][3][r]);
                float c_new = fg * cv[ml][r] + ig * gg;
                cv[ml][r] = c_new;
                h_wr[idx] = f2bf(og * fast_tanh(c_new));
            }
        }
    }
}

// Persistent pipelined ConvLSTM: per-tile dataflow flags instead of grid barriers.
// Block b owns tiles {b, b+768, b+1536}. flag[t][j] set => tile j's step-t h
// written AND all its step-t halo reads complete (covers ping-pong overwrite).
__global__ __launch_bounds__(256, 3)
void convlstm_flags_kernel(const unsigned short* __restrict__ xp,
                           unsigned short* __restrict__ h_a,
                           unsigned short* __restrict__ h_b,
                           floatx4* __restrict__ c_ws,
                           const unsigned short* __restrict__ Wfrag,
                           const float* __restrict__ bias,
                           unsigned int* __restrict__ flags) {
    __shared__ unsigned short tile[NPX * STRIDE];   // 27.2 KB

    const int tid  = threadIdx.x;
    const int lane = tid & 63;
    const int wave = tid >> 6;
    const int u    = lane & 15;
    const int quad = lane >> 4;
    const int b    = (int)blockIdx.x;
    const int nt   = (b < NTILE - 2 * NBLKP) ? 3 : 2;   // b<512 ? 3 : 2

    float bg[4];
    #pragma unroll
    for (int g = 0; g < 4; ++g) bg[g] = bias[g * 16 + u];

    int abase[4];
    #pragma unroll
    for (int ml = 0; ml < 4; ++ml) {
        int m  = wave + ml * 4;
        int my = m >> 1;
        int mx = (m & 1) << 4;
        abase[ml] = (my * HALO_X + mx + u) * STRIDE + quad * 8;
    }

    #pragma unroll 1
    for (int t = 0; t < TT; ++t) {
        const unsigned short* h_rd = (t & 1) ? h_a : h_b;
        unsigned short*       h_wr = (t & 1) ? h_b : h_a;
        const int first = (t == 0);

        // ---- upfront poll: step t-1 flags of the 9 neighbors of each owned tile ----
        if (!first) {
            if (tid < 9 * nt) {
                int s  = tid / 9;
                int k  = tid - s * 9;
                int j  = b + s * NBLKP;
                int dy = k / 3 - 1;
                int dx = k - (k / 3) * 3 - 1;
                int bbj = j >> 8;
                int rm  = j & 255;
                int ny  = (rm >> 3) + dy;
                int nx  = (rm & 7) + dx;
                if (ny >= 0 && ny < 32 && nx >= 0 && nx < 8) {
                    unsigned int* f = &flags[(unsigned)(t - 1) * NTILE
                                             + (unsigned)((bbj * 32 + ny) * 8 + nx)];
                    while (atomicAdd(f, 0u) == 0u) __builtin_amdgcn_s_sleep(4);
                }
            }
            __syncthreads();
            __threadfence();   // acquire: invalidate stale h lines before staging
        }

        #pragma unroll 1
        for (int s = 0; s < nt; ++s) {
            const int j  = b + s * NBLKP;
            const int bb = j >> 8;
            const int rm = j & 255;
            const int y0 = (rm >> 3) * TY;
            const int x0 = (rm & 7) * TX;

            __syncthreads();   // previous compute's LDS reads done
            stage_tile(tile, tid, bb, y0, x0, t, first, xp, h_rd);

            floatx4 cv[4];
            const size_t cbase = ((size_t)j * 4 + wave) * 64 + lane;
            if (!first) {
                #pragma unroll
                for (int ml = 0; ml < 4; ++ml) cv[ml] = c_ws[cbase * 4 + ml];
            } else {
                #pragma unroll
                for (int ml = 0; ml < 4; ++ml) cv[ml] = (floatx4){0.f, 0.f, 0.f, 0.f};
            }
            __syncthreads();

            compute_tile(tile, Wfrag, bg, abase, bb, y0, x0,
                         lane, wave, u, quad, cv, h_wr);

            #pragma unroll
            for (int ml = 0; ml < 4; ++ml) c_ws[cbase * 4 + ml] = cv[ml];
        }

        // ---- release: publish this block's step-t tiles ----
        __threadfence();
        __syncthreads();
        if (tid < nt)
            atomicExch(&flags[(unsigned)t * NTILE + (unsigned)(b + tid * NBLKP)], 1u);
    }
}

// Fallback: one step per launch (proven R4 structure + coalesced c).
__global__ __launch_bounds__(256, 4)
void convlstm_step_kernel(const unsigned short* __restrict__ xp, int t,
                          const unsigned short* __restrict__ h_in,
                          unsigned short* __restrict__ h_out,
                          floatx4* __restrict__ c_ws,
                          const unsigned short* __restrict__ Wfrag,
                          const float* __restrict__ bias,
                          int first) {
    __shared__ unsigned short tile[NPX * STRIDE];

    const int tid  = threadIdx.x;
    const int lane = tid & 63;
    const int wave = tid >> 6;
    const int u    = lane & 15;
    const int quad = lane >> 4;
    const int x0 = blockIdx.x * TX;
    const int y0 = blockIdx.y * TY;
    const int bb = blockIdx.z;
    const int tileid = (bb * 32 + (int)blockIdx.y) * 8 + (int)blockIdx.x;

    float bg[4];
    #pragma unroll
    for (int g = 0; g < 4; ++g) bg[g] = bias[g * 16 + u];

    int abase[4];
    #pragma unroll
    for (int ml = 0; ml < 4; ++ml) {
        int m  = wave + ml * 4;
        int my = m >> 1;
        int mx = (m & 1) << 4;
        abase[ml] = (my * HALO_X + mx + u) * STRIDE + quad * 8;
    }

    stage_tile(tile, tid, bb, y0, x0, t, first, xp, h_in);

    floatx4 cv[4];
    const size_t cbase = ((size_t)tileid * 4 + wave) * 64 + lane;
    if (!first) {
        #pragma unroll
        for (int ml = 0; ml < 4; ++ml) cv[ml] = c_ws[cbase * 4 + ml];
    } else {
        #pragma unroll
        for (int ml = 0; ml < 4; ++ml) cv[ml] = (floatx4){0.f, 0.f, 0.f, 0.f};
    }
    __syncthreads();

    compute_tile(tile, Wfrag, bg, abase, bb, y0, x0,
                 lane, wave, u, quad, cv, h_out);

    #pragma unroll
    for (int ml = 0; ml < 4; ++ml) c_ws[cbase * 4 + ml] = cv[ml];
}

// Final 1x1 conv from bf16 channel-last h
__global__ void final_conv_kernel(const unsigned short* __restrict__ h,
                                  const float* __restrict__ Wf,
                                  const float* __restrict__ bf_,
                                  float* __restrict__ out) {
    int i = blockIdx.x * 256 + threadIdx.x;
    if (i >= BB * HH * WW) return;
    size_t base = (size_t)i * HIDDEN;
    uint4 v0 = *(const uint4*)&h[base];
    uint4 v1 = *(const uint4*)&h[base + 8];
    const unsigned short* p0 = (const unsigned short*)&v0;
    const unsigned short* p1 = (const unsigned short*)&v1;
    float s = bf_[0];
    #pragma unroll
    for (int k = 0; k < 8; ++k) s += Wf[k] * bf2f(p0[k]);
    #pragma unroll
    for (int k = 0; k < 8; ++k) s += Wf[8 + k] * bf2f(p1[k]);
    out[i] = s;
}

extern "C" void kernel_launch(void* const* d_in, const int* in_sizes, int n_in,
                              void* d_out, int out_size, void* d_ws, size_t ws_size,
                              hipStream_t stream) {
    const float* x  = (const float*)d_in[0];
    const float* Wc = (const float*)d_in[1];
    const float* bc = (const float*)d_in[2];
    const float* Wf = (const float*)d_in[3];
    const float* bf = (const float*)d_in[4];
    float* out = (float*)d_out;

    char* ws = (char*)d_ws;
    const size_t h_bytes = (size_t)BB * HH * WW * HIDDEN * 2;   // 16.78 MB
    const size_t w_bytes = 64 * 1024;                           // Wfrag (36.9 KB used)
    const size_t x_bytes = (size_t)BB * TT * HH * WW * 8 * 2;   // 100.7 MB
    const size_t c_bytes = (size_t)BB * HH * WW * HIDDEN * 4;   // 33.55 MB

    unsigned short* h_a = (unsigned short*)(ws);
    unsigned short* h_b = (unsigned short*)(ws + h_bytes);
    unsigned short* Wfr = (unsigned short*)(ws + 2 * h_bytes);
    unsigned short* xp  = (unsigned short*)(ws + 2 * h_bytes + w_bytes);
    floatx4* c_ws       = (floatx4*)(ws + 2 * h_bytes + w_bytes + x_bytes);
    unsigned int* flags = (unsigned int*)(ws + 2 * h_bytes + w_bytes + x_bytes + c_bytes);
    (void)ws_size;

    prep_w_kernel<<<(9 * 4 * 64 * 8 + 255) / 256, 256, 0, stream>>>(Wc, Wfr);
    {
        size_t totpx = (size_t)BB * TT * HH * WW;
        prep_x_kernel<<<(int)((totpx + 255) / 256), 256, 0, stream>>>(x, xp);
    }
    init_flags_kernel<<<(TT * NTILE + 255) / 256, 256, 0, stream>>>(flags);

    void* args[] = {(void*)&xp, (void*)&h_a, (void*)&h_b, (void*)&c_ws,
                    (void*)&Wfr, (void*)&bc, (void*)&flags};
    hipError_t cerr = hipLaunchCooperativeKernel(
        (void*)convlstm_flags_kernel, dim3(NBLKP), dim3(256), args, 0, stream);

    if (cerr != hipSuccess) {
        (void)hipGetLastError();   // clear error state
        dim3 grid(WW / TX, HH / TY, BB);
        dim3 block(256, 1, 1);
        const unsigned short* h_in = h_a;
        for (int t = 0; t < TT; ++t) {
            unsigned short* h_out = (t & 1) ? h_b : h_a;
            convlstm_step_kernel<<<grid, block, 0, stream>>>(
                xp, t, h_in, h_out, c_ws, Wfr, bc, (t == 0) ? 1 : 0);
            h_in = h_out;
        }
    }

    // TT=12 -> last write (t=11, odd) is h_b on both paths
    final_conv_kernel<<<(BB * HH * WW + 255) / 256, 256, 0, stream>>>(
        h_b, Wf, bf, out);
}